// Round 1
// baseline (1466.468 us; speedup 1.0000x reference)
//
#include <hip/hip_runtime.h>
#include <hip/hip_bf16.h>

#define TOKENS 2048
#define HDIM   2560
#define NEXP   16
#define IDIM   1664
#define ISDIM  3328
#define NPAIR  (TOKENS*2)

typedef float  f32x4   __attribute__((ext_vector_type(4)));
typedef __bf16 bf16x8  __attribute__((ext_vector_type(8)));
typedef short  short4v __attribute__((ext_vector_type(4)));

__device__ __forceinline__ short f2bf(float f) {
  unsigned u = __builtin_bit_cast(unsigned, f);
  u += 0x7FFFu + ((u >> 16) & 1u);          // RNE to bf16
  return (short)(u >> 16);
}

// ---------------- router: fp32 logits, softmax-top2-renorm == sigmoid(l0-l1)
__global__ void router_kernel(const float* __restrict__ x, const float* __restrict__ rw,
                              int* __restrict__ counts, int* __restrict__ tidx,
                              float* __restrict__ tw) {
  const int t = blockIdx.x;
  const int lane = threadIdx.x;
  float acc[NEXP];
#pragma unroll
  for (int e = 0; e < NEXP; ++e) acc[e] = 0.f;
  const float* xr = x + (size_t)t * HDIM;
  for (int k = lane; k < HDIM; k += 64) {
    float xv = xr[k];
#pragma unroll
    for (int e = 0; e < NEXP; ++e) acc[e] += xv * rw[e * HDIM + k];
  }
#pragma unroll
  for (int e = 0; e < NEXP; ++e) {
#pragma unroll
    for (int o = 32; o > 0; o >>= 1) acc[e] += __shfl_down(acc[e], o);
  }
  if (lane == 0) {
    int i0 = 0; float v0 = acc[0];
#pragma unroll
    for (int e = 1; e < NEXP; ++e) if (acc[e] > v0) { v0 = acc[e]; i0 = e; }
    int i1 = -1; float v1 = -3.4e38f;
#pragma unroll
    for (int e = 0; e < NEXP; ++e) if (e != i0 && acc[e] > v1) { v1 = acc[e]; i1 = e; }
    float w0 = 1.f / (1.f + expf(v1 - v0));
    tidx[t * 2] = i0; tidx[t * 2 + 1] = i1;
    tw[t * 2] = w0;   tw[t * 2 + 1] = 1.f - w0;
    atomicAdd(&counts[i0], 1);
    atomicAdd(&counts[i1], 1);
  }
}

__global__ void scan_kernel(const int* __restrict__ counts, int* __restrict__ offsets) {
  if (threadIdx.x == 0) {
    int a = 0;
    for (int e = 0; e < NEXP; ++e) { offsets[e] = a; a += counts[e]; }
  }
}

// ---------------- bucket pairs + gather bf16 activations
__global__ void gather_kernel(const float* __restrict__ x, const int* __restrict__ tidx,
                              const float* __restrict__ tw, const int* __restrict__ offsets,
                              int* __restrict__ slotc, int* __restrict__ rowmap,
                              float* __restrict__ wrow, short* __restrict__ xb,
                              short* __restrict__ xg) {
  const int t = blockIdx.x, tid = threadIdx.x;
  __shared__ int grs[2];
  if (tid < 2) {
    int e = tidx[t * 2 + tid];
    int slot = atomicAdd(&slotc[e], 1);
    int g = offsets[e] + slot;
    grs[tid] = g;
    rowmap[g] = t * 2 + tid;
    wrow[g] = tw[t * 2 + tid];
  }
  __syncthreads();
  const int g0 = grs[0], g1 = grs[1];
  const float* xr = x + (size_t)t * HDIM;
#pragma unroll
  for (int i = 0; i < HDIM / 256; ++i) {
    int k = tid + i * 256;
    short v = f2bf(xr[k]);
    xb[(size_t)t * HDIM + k] = v;
    xg[(size_t)g0 * HDIM + k] = v;
    xg[(size_t)g1 * HDIM + k] = v;
  }
}

__global__ void silu_mul_kernel(const float* __restrict__ g, const float* __restrict__ u,
                                short* __restrict__ h, long n4) {
  long i = (long)blockIdx.x * 256 + threadIdx.x;
  const long stride = (long)gridDim.x * 256;
  for (; i < n4; i += stride) {
    float4 gv = ((const float4*)g)[i];
    float4 uv = ((const float4*)u)[i];
    short4v o;
    o[0] = f2bf(gv.x / (1.f + expf(-gv.x)) * uv.x);
    o[1] = f2bf(gv.y / (1.f + expf(-gv.y)) * uv.y);
    o[2] = f2bf(gv.z / (1.f + expf(-gv.z)) * uv.z);
    o[3] = f2bf(gv.w / (1.f + expf(-gv.w)) * uv.w);
    ((short4v*)h)[i] = o;
  }
}

// ---------------- GEMM-TN: A bf16 (M,K) K-contig; B fp32 (K,N) N-contig,
// converted+transposed into LDS during staging. 128x128 tile, BK=32, 4 waves.
// MODE 0: plain f32 store.  MODE 1: expert rows, f32 store at global row.
// MODE 2: expert rows, scale by wrow, scatter to pairs[rowmap[row]].
// MODE 3: out = acc + pairs[2t] + pairs[2t+1]  (shared down + combine).
template <int MODE>
__launch_bounds__(256, 2)
__global__ void gemm_tn(const short* __restrict__ A, const float* __restrict__ Bw,
                        float* __restrict__ Out, const int K, const int N,
                        const int* __restrict__ counts, const int* __restrict__ offsets,
                        const int* __restrict__ rowmap, const float* __restrict__ wrow,
                        const float* __restrict__ pairs, const int MAmax) {
  const int tid = threadIdx.x;
  const int lane = tid & 63;
  const int wv = tid >> 6;
  const int wm = (wv >> 1) * 64;
  const int wn = (wv & 1) * 64;
  const int ntile = blockIdx.x * 128;
  const int mtile = blockIdx.y * 128;

  int rowbase = 0;
  int cnt = 0x7fffffff;
  const float* B = Bw;
  if (MODE == 1 || MODE == 2) {
    const int e = blockIdx.z;
    cnt = counts[e];
    if (mtile >= cnt) return;
    rowbase = offsets[e];
    B = Bw + (size_t)e * K * N;
  }

  __shared__ short Ab[2][128][40];   // rows 80B => every row 16B-aligned
  __shared__ short Bb[2][128][40];   // transposed weight tile [n][k], XOR k-group swizzle

  f32x4 acc[4][4];
#pragma unroll
  for (int i = 0; i < 4; ++i)
#pragma unroll
    for (int j = 0; j < 4; ++j) { f32x4 z = {0.f, 0.f, 0.f, 0.f}; acc[i][j] = z; }

  const int KT = K >> 5;

  int4 aReg[2];
  float2 bReg[2][4];
  const int a_r0 = (tid >> 2);
  const int a_k = (tid & 3) << 3;
  const int b_n0 = (tid & 63) * 2;
  const int b_k0q = (tid >> 6) * 4;

  auto loadA = [&](int kt) {
    const int kb = kt << 5;
#pragma unroll
    for (int i = 0; i < 2; ++i) {
      int rt = mtile + a_r0 + i * 64;
      int gabs;
      if (MODE == 1 || MODE == 2) {
        gabs = rowbase + rt;
        if (gabs > MAmax - 1) gabs = MAmax - 1;   // padded tail rows: read safe, never stored
      } else gabs = rt;
      aReg[i] = *reinterpret_cast<const int4*>(A + (size_t)gabs * K + kb + a_k);
    }
  };
  auto writeA = [&](int buf) {
#pragma unroll
    for (int i = 0; i < 2; ++i)
      *reinterpret_cast<int4*>(&Ab[buf][a_r0 + i * 64][a_k]) = aReg[i];
  };
  auto loadB = [&](int kt) {
    const int kb = kt << 5;
#pragma unroll
    for (int j = 0; j < 2; ++j) {
      const int k0 = j * 16 + b_k0q;
#pragma unroll
      for (int kk = 0; kk < 4; ++kk)
        bReg[j][kk] = *reinterpret_cast<const float2*>(B + (size_t)(kb + k0 + kk) * N + ntile + b_n0);
    }
  };
  auto writeB = [&](int buf) {
#pragma unroll
    for (int j = 0; j < 2; ++j) {
      const int k0 = j * 16 + b_k0q;
#pragma unroll
      for (int nn = 0; nn < 2; ++nn) {
        const int n = b_n0 + nn;
        const int kp = (k0 & 7) | ((((k0 >> 3) ^ n) & 3) << 3);
        short4v p;
        p[0] = f2bf(nn ? bReg[j][0].y : bReg[j][0].x);
        p[1] = f2bf(nn ? bReg[j][1].y : bReg[j][1].x);
        p[2] = f2bf(nn ? bReg[j][2].y : bReg[j][2].x);
        p[3] = f2bf(nn ? bReg[j][3].y : bReg[j][3].x);
        *reinterpret_cast<short4v*>(&Bb[buf][n][kp]) = p;
      }
    }
  };

  const int lrow = lane & 15;
  const int lkg = lane >> 4;
  auto compute = [&](int buf) {
    bf16x8 af[4], bfv[4];
#pragma unroll
    for (int mf = 0; mf < 4; ++mf)
      af[mf] = *reinterpret_cast<const bf16x8*>(&Ab[buf][wm + mf * 16 + lrow][lkg << 3]);
#pragma unroll
    for (int nf = 0; nf < 4; ++nf) {
      const int n = wn + nf * 16 + lrow;
      const int kg = ((lkg ^ n) & 3) << 3;
      bfv[nf] = *reinterpret_cast<const bf16x8*>(&Bb[buf][n][kg]);
    }
#pragma unroll
    for (int mf = 0; mf < 4; ++mf)
#pragma unroll
      for (int nf = 0; nf < 4; ++nf)
        acc[mf][nf] = __builtin_amdgcn_mfma_f32_16x16x32_bf16(af[mf], bfv[nf], acc[mf][nf], 0, 0, 0);
  };

  loadA(0); loadB(0);
  writeA(0); writeB(0);
  __syncthreads();
  for (int kt = 0; kt < KT; ++kt) {
    const int buf = kt & 1;
    if (kt + 1 < KT) { loadA(kt + 1); loadB(kt + 1); }
    compute(buf);
    if (kt + 1 < KT) { writeA(buf ^ 1); writeB(buf ^ 1); }
    __syncthreads();
  }

  // epilogue: C/D layout col=lane&15, row=(lane>>4)*4+r   [m89-verified]
#pragma unroll
  for (int mf = 0; mf < 4; ++mf) {
#pragma unroll
    for (int r = 0; r < 4; ++r) {
      const int rtile = wm + mf * 16 + ((lane >> 4) << 2) + r;
      const int colb = ntile + wn + (lane & 15);
      if (MODE == 0) {
        float* o = Out + (size_t)(mtile + rtile) * N + colb;
#pragma unroll
        for (int nf = 0; nf < 4; ++nf) o[nf * 16] = acc[mf][nf][r];
      } else if (MODE == 1) {
        if (mtile + rtile < cnt) {
          float* o = Out + (size_t)(rowbase + mtile + rtile) * N + colb;
#pragma unroll
          for (int nf = 0; nf < 4; ++nf) o[nf * 16] = acc[mf][nf][r];
        }
      } else if (MODE == 2) {
        if (mtile + rtile < cnt) {
          const int gr = rowbase + mtile + rtile;
          const int pid = rowmap[gr];
          const float wwv = wrow[gr];
          float* o = Out + (size_t)pid * N + colb;
#pragma unroll
          for (int nf = 0; nf < 4; ++nf) o[nf * 16] = wwv * acc[mf][nf][r];
        }
      } else {
        const int t = mtile + rtile;
        const float* p0 = pairs + (size_t)(2 * t) * N + colb;
        const float* p1 = p0 + N;
        float* o = Out + (size_t)t * N + colb;
#pragma unroll
        for (int nf = 0; nf < 4; ++nf) o[nf * 16] = acc[mf][nf][r] + p0[nf * 16] + p1[nf * 16];
      }
    }
  }
}

extern "C" void kernel_launch(void* const* d_in, const int* in_sizes, int n_in,
                              void* d_out, int out_size, void* d_ws, size_t ws_size,
                              hipStream_t stream) {
  const float* x  = (const float*)d_in[0];
  const float* rw = (const float*)d_in[1];
  const float* w1 = (const float*)d_in[2];
  const float* w3 = (const float*)d_in[3];
  const float* w2 = (const float*)d_in[4];
  const float* sg = (const float*)d_in[5];
  const float* su = (const float*)d_in[6];
  const float* sd = (const float*)d_in[7];
  float* out = (float*)d_out;
  (void)in_sizes; (void)n_in; (void)out_size; (void)ws_size;

  char* ws = (char*)d_ws;
  size_t off = 0;
  auto alloc = [&](size_t bytes) -> void* {
    void* p = ws + off;
    off = (off + bytes + 255) & ~(size_t)255;
    return p;
  };
  int*   counts  = (int*)alloc(NEXP * 4);          // @0
  int*   slotc   = (int*)alloc(NEXP * 4);          // @256
  int*   offsets = (int*)alloc(NEXP * 4);
  int*   tidx    = (int*)alloc(NPAIR * 4);
  float* tw      = (float*)alloc(NPAIR * 4);
  int*   rowmap  = (int*)alloc(NPAIR * 4);
  float* wrowv   = (float*)alloc(NPAIR * 4);
  short* xb      = (short*)alloc((size_t)TOKENS * HDIM * 2);
  short* xg      = (short*)alloc((size_t)NPAIR * HDIM * 2);
  short* hbuf    = (short*)alloc((size_t)NPAIR * IDIM * 2);   // == TOKENS*ISDIM
  float* gbuf    = (float*)alloc((size_t)NPAIR * IDIM * 4);   // reused by shared phase
  float* ubuf    = (float*)alloc((size_t)NPAIR * IDIM * 4);
  float* pairs   = (float*)alloc((size_t)NPAIR * HDIM * 4);

  hipMemsetAsync(d_ws, 0, 512, stream);  // zero counts + slotc

  router_kernel<<<dim3(TOKENS), dim3(64), 0, stream>>>(x, rw, counts, tidx, tw);
  scan_kernel<<<dim3(1), dim3(64), 0, stream>>>(counts, offsets);
  gather_kernel<<<dim3(TOKENS), dim3(256), 0, stream>>>(x, tidx, tw, offsets, slotc,
                                                        rowmap, wrowv, xb, xg);

  // sparse experts
  gemm_tn<1><<<dim3(IDIM / 128, 16, NEXP), dim3(256), 0, stream>>>(
      xg, w1, gbuf, HDIM, IDIM, counts, offsets, nullptr, nullptr, nullptr, NPAIR);
  gemm_tn<1><<<dim3(IDIM / 128, 16, NEXP), dim3(256), 0, stream>>>(
      xg, w3, ubuf, HDIM, IDIM, counts, offsets, nullptr, nullptr, nullptr, NPAIR);
  silu_mul_kernel<<<dim3(2048), dim3(256), 0, stream>>>(gbuf, ubuf, hbuf,
                                                        (long)NPAIR * IDIM / 4);
  gemm_tn<2><<<dim3(HDIM / 128, 16, NEXP), dim3(256), 0, stream>>>(
      hbuf, w2, pairs, IDIM, HDIM, counts, offsets, rowmap, wrowv, nullptr, NPAIR);

  // shared MLP (+ combine in epilogue)
  gemm_tn<0><<<dim3(ISDIM / 128, TOKENS / 128, 1), dim3(256), 0, stream>>>(
      xb, sg, gbuf, HDIM, ISDIM, nullptr, nullptr, nullptr, nullptr, nullptr, TOKENS);
  gemm_tn<0><<<dim3(ISDIM / 128, TOKENS / 128, 1), dim3(256), 0, stream>>>(
      xb, su, ubuf, HDIM, ISDIM, nullptr, nullptr, nullptr, nullptr, nullptr, TOKENS);
  silu_mul_kernel<<<dim3(2048), dim3(256), 0, stream>>>(gbuf, ubuf, hbuf,
                                                        (long)TOKENS * ISDIM / 4);
  gemm_tn<3><<<dim3(HDIM / 128, TOKENS / 128, 1), dim3(256), 0, stream>>>(
      hbuf, sd, out, ISDIM, HDIM, nullptr, nullptr, nullptr, nullptr, pairs, TOKENS);
}

// Round 2
// 1305.339 us; speedup vs baseline: 1.1234x; 1.1234x over previous
//
#include <hip/hip_runtime.h>
#include <hip/hip_bf16.h>

#define TOKENS 2048
#define HDIM   2560
#define NEXP   16
#define IDIM   1664
#define ISDIM  3328
#define NPAIR  (TOKENS*2)

typedef float  f32x4   __attribute__((ext_vector_type(4)));
typedef __bf16 bf16x8  __attribute__((ext_vector_type(8)));
typedef short  short4v __attribute__((ext_vector_type(4)));
typedef short  short2v __attribute__((ext_vector_type(2)));

__device__ __forceinline__ short f2bf(float f) {
  unsigned u = __builtin_bit_cast(unsigned, f);
  u += 0x7FFFu + ((u >> 16) & 1u);          // RNE to bf16
  return (short)(u >> 16);
}

// ---------------- router: fp32 logits, softmax-top2-renorm == sigmoid(l0-l1)
__global__ void router_kernel(const float* __restrict__ x, const float* __restrict__ rw,
                              int* __restrict__ counts, int* __restrict__ tidx,
                              float* __restrict__ tw) {
  const int t = blockIdx.x;
  const int lane = threadIdx.x;
  float acc[NEXP];
#pragma unroll
  for (int e = 0; e < NEXP; ++e) acc[e] = 0.f;
  const float* xr = x + (size_t)t * HDIM;
  for (int k = lane; k < HDIM; k += 64) {
    float xv = xr[k];
#pragma unroll
    for (int e = 0; e < NEXP; ++e) acc[e] += xv * rw[e * HDIM + k];
  }
#pragma unroll
  for (int e = 0; e < NEXP; ++e) {
#pragma unroll
    for (int o = 32; o > 0; o >>= 1) acc[e] += __shfl_down(acc[e], o);
  }
  if (lane == 0) {
    int i0 = 0; float v0 = acc[0];
#pragma unroll
    for (int e = 1; e < NEXP; ++e) if (acc[e] > v0) { v0 = acc[e]; i0 = e; }
    int i1 = -1; float v1 = -3.4e38f;
#pragma unroll
    for (int e = 0; e < NEXP; ++e) if (e != i0 && acc[e] > v1) { v1 = acc[e]; i1 = e; }
    float w0 = 1.f / (1.f + expf(v1 - v0));
    tidx[t * 2] = i0; tidx[t * 2 + 1] = i1;
    tw[t * 2] = w0;   tw[t * 2 + 1] = 1.f - w0;
    atomicAdd(&counts[i0], 1);
    atomicAdd(&counts[i1], 1);
  }
}

__global__ void scan_kernel(const int* __restrict__ counts, int* __restrict__ offsets) {
  if (threadIdx.x == 0) {
    int a = 0;
    for (int e = 0; e < NEXP; ++e) { offsets[e] = a; a += counts[e]; }
  }
}

// ---------------- bucket pairs + gather bf16 activations
__global__ void gather_kernel(const float* __restrict__ x, const int* __restrict__ tidx,
                              const float* __restrict__ tw, const int* __restrict__ offsets,
                              int* __restrict__ slotc, int* __restrict__ rowmap,
                              float* __restrict__ wrow, short* __restrict__ xb,
                              short* __restrict__ xg) {
  const int t = blockIdx.x, tid = threadIdx.x;
  __shared__ int grs[2];
  if (tid < 2) {
    int e = tidx[t * 2 + tid];
    int slot = atomicAdd(&slotc[e], 1);
    int g = offsets[e] + slot;
    grs[tid] = g;
    rowmap[g] = t * 2 + tid;
    wrow[g] = tw[t * 2 + tid];
  }
  __syncthreads();
  const int g0 = grs[0], g1 = grs[1];
  const float* xr = x + (size_t)t * HDIM;
#pragma unroll
  for (int i = 0; i < HDIM / 256; ++i) {
    int k = tid + i * 256;
    short v = f2bf(xr[k]);
    xb[(size_t)t * HDIM + k] = v;
    xg[(size_t)g0 * HDIM + k] = v;
    xg[(size_t)g1 * HDIM + k] = v;
  }
}

// ================= fused up-proj: H = bf16( silu(A·B1) * (A·B3) )
// A bf16 (M,K) K-contig. B1,B3 fp32 (K,N) N-contig (per-expert slabs if EXPERT).
// BM=256, BN=64, BK=32, 512 threads (8 waves: 4 in M x 2 in N, wave tile 64x32).
template <bool EXPERT>
__launch_bounds__(512, 2)
__global__ void moe_up(const short* __restrict__ A, const float* __restrict__ B1w,
                       const float* __restrict__ B3w, short* __restrict__ H,
                       const int K, const int N,
                       const int* __restrict__ counts, const int* __restrict__ offsets,
                       const int MAmax) {
  const int tid = threadIdx.x;
  const int lane = tid & 63;
  const int wv = tid >> 6;
  const int wm = (wv >> 1) * 64;
  const int wn = (wv & 1) * 32;
  const int ntile = blockIdx.x * 64;
  const int mtile = blockIdx.y * 256;

  int rowbase = 0, cnt = 0x7fffffff;
  const float* B1 = B1w;
  const float* B3 = B3w;
  if (EXPERT) {
    const int e = blockIdx.z;
    cnt = counts[e];
    if (mtile >= cnt) return;
    rowbase = offsets[e];
    B1 = B1w + (size_t)e * K * N;
    B3 = B3w + (size_t)e * K * N;
  }

  __shared__ short Ab[2][256][40];      // 40 KB
  __shared__ short Bb[2][2][64][40];    // 20 KB (two weight matrices, k-swizzled)

  f32x4 accG[4][2], accU[4][2];
#pragma unroll
  for (int i = 0; i < 4; ++i)
#pragma unroll
    for (int j = 0; j < 2; ++j) {
      f32x4 z = {0.f, 0.f, 0.f, 0.f};
      accG[i][j] = z; accU[i][j] = z;
    }

  const int KT = K >> 5;

  const int a_r0 = tid >> 2;            // 0..127
  const int a_k  = (tid & 3) << 3;      // 0,8,16,24
  int4 aReg[2];

  const int sm   = tid >> 8;            // which B matrix this thread stages
  const int t8   = tid & 255;
  const int b_n0 = (t8 & 31) * 2;       // 0..62
  const int b_k0 = (t8 >> 5) * 4;       // 0..28
  const float* Bs = sm ? B3 : B1;
  float2 bReg[4];

  auto loadA = [&](int kt) {
    const int kb = kt << 5;
#pragma unroll
    for (int i = 0; i < 2; ++i) {
      int rt = mtile + a_r0 + i * 128;
      int gabs;
      if (EXPERT) {
        gabs = rowbase + rt;
        if (gabs > MAmax - 1) gabs = MAmax - 1;   // tail rows: safe read, never stored
      } else gabs = rt;
      aReg[i] = *reinterpret_cast<const int4*>(A + (size_t)gabs * K + kb + a_k);
    }
  };
  auto writeA = [&](int buf) {
#pragma unroll
    for (int i = 0; i < 2; ++i)
      *reinterpret_cast<int4*>(&Ab[buf][a_r0 + i * 128][a_k]) = aReg[i];
  };
  auto loadB = [&](int kt) {
    const int kb = kt << 5;
#pragma unroll
    for (int kk = 0; kk < 4; ++kk)
      bReg[kk] = *reinterpret_cast<const float2*>(Bs + (size_t)(kb + b_k0 + kk) * N + ntile + b_n0);
  };
  auto writeB = [&](int buf) {
#pragma unroll
    for (int nn = 0; nn < 2; ++nn) {
      const int n = b_n0 + nn;
      const int kp = (b_k0 & 7) | ((((b_k0 >> 3) ^ n) & 3) << 3);
      short4v p;
      p[0] = f2bf(nn ? bReg[0].y : bReg[0].x);
      p[1] = f2bf(nn ? bReg[1].y : bReg[1].x);
      p[2] = f2bf(nn ? bReg[2].y : bReg[2].x);
      p[3] = f2bf(nn ? bReg[3].y : bReg[3].x);
      *reinterpret_cast<short4v*>(&Bb[buf][sm][n][kp]) = p;
    }
  };

  const int lrow = lane & 15;
  const int lkg = lane >> 4;
  auto compute = [&](int buf) {
    bf16x8 af[4], bg[2], bu[2];
#pragma unroll
    for (int mf = 0; mf < 4; ++mf)
      af[mf] = *reinterpret_cast<const bf16x8*>(&Ab[buf][wm + mf * 16 + lrow][lkg << 3]);
#pragma unroll
    for (int nf = 0; nf < 2; ++nf) {
      const int n = wn + nf * 16 + lrow;
      const int kg = ((lkg ^ n) & 3) << 3;
      bg[nf] = *reinterpret_cast<const bf16x8*>(&Bb[buf][0][n][kg]);
      bu[nf] = *reinterpret_cast<const bf16x8*>(&Bb[buf][1][n][kg]);
    }
#pragma unroll
    for (int mf = 0; mf < 4; ++mf)
#pragma unroll
      for (int nf = 0; nf < 2; ++nf) {
        accG[mf][nf] = __builtin_amdgcn_mfma_f32_16x16x32_bf16(af[mf], bg[nf], accG[mf][nf], 0, 0, 0);
        accU[mf][nf] = __builtin_amdgcn_mfma_f32_16x16x32_bf16(af[mf], bu[nf], accU[mf][nf], 0, 0, 0);
      }
  };

  loadA(0); loadB(0);
  writeA(0); writeB(0);
  __syncthreads();
  for (int kt = 0; kt < KT; ++kt) {
    const int buf = kt & 1;
    if (kt + 1 < KT) { loadA(kt + 1); loadB(kt + 1); }
    compute(buf);
    if (kt + 1 < KT) { writeA(buf ^ 1); writeB(buf ^ 1); }
    __syncthreads();
  }

  // epilogue: silu(g)*u -> bf16.  C/D layout col=lane&15, row=(lane>>4)*4+r
#pragma unroll
  for (int mf = 0; mf < 4; ++mf) {
#pragma unroll
    for (int r = 0; r < 4; ++r) {
      const int rtile = wm + mf * 16 + ((lane >> 4) << 2) + r;
      if (EXPERT && mtile + rtile >= cnt) continue;
      const size_t grow = (size_t)((EXPERT ? rowbase : 0) + mtile + rtile);
      const int col = ntile + wn + (lane & 15);
#pragma unroll
      for (int nf = 0; nf < 2; ++nf) {
        float g = accG[mf][nf][r];
        float u = accU[mf][nf][r];
        float h = g / (1.f + expf(-g)) * u;
        H[grow * N + col + nf * 16] = f2bf(h);
      }
    }
  }
}

// ================= down-proj: Out = A·B (+ scatter/scale or combine)
// A bf16 (M,K) K-contig; B fp32 (K,N) N-contig. BM=256, BN=64, BK=32, 512 thr.
// MODE 2: expert rows, scale by wrow, scatter to pairs[rowmap[row]].
// MODE 3: out = acc + pairs[2t] + pairs[2t+1]  (shared down + combine).
template <int MODE>
__launch_bounds__(512, 2)
__global__ void moe_down(const short* __restrict__ A, const float* __restrict__ Bw,
                         float* __restrict__ Out, const int K, const int N,
                         const int* __restrict__ counts, const int* __restrict__ offsets,
                         const int* __restrict__ rowmap, const float* __restrict__ wrow,
                         const float* __restrict__ pairs, const int MAmax) {
  const int tid = threadIdx.x;
  const int lane = tid & 63;
  const int wv = tid >> 6;
  const int wm = (wv >> 1) * 64;
  const int wn = (wv & 1) * 32;
  const int ntile = blockIdx.x * 64;
  const int mtile = blockIdx.y * 256;

  int rowbase = 0, cnt = 0x7fffffff;
  const float* B = Bw;
  if (MODE == 2) {
    const int e = blockIdx.z;
    cnt = counts[e];
    if (mtile >= cnt) return;
    rowbase = offsets[e];
    B = Bw + (size_t)e * K * N;
  }

  __shared__ short Ab[2][256][40];   // 40 KB
  __shared__ short Bb[2][64][40];    // 10 KB

  f32x4 acc[4][2];
#pragma unroll
  for (int i = 0; i < 4; ++i)
#pragma unroll
    for (int j = 0; j < 2; ++j) { f32x4 z = {0.f, 0.f, 0.f, 0.f}; acc[i][j] = z; }

  const int KT = K >> 5;

  const int a_r0 = tid >> 2;
  const int a_k  = (tid & 3) << 3;
  int4 aReg[2];

  const int b_n0 = (tid & 31) * 2;     // 0..62
  const int b_k0 = (tid >> 5) * 2;     // 0..30 (even)
  float2 bReg[2];

  auto loadA = [&](int kt) {
    const int kb = kt << 5;
#pragma unroll
    for (int i = 0; i < 2; ++i) {
      int rt = mtile + a_r0 + i * 128;
      int gabs;
      if (MODE == 2) {
        gabs = rowbase + rt;
        if (gabs > MAmax - 1) gabs = MAmax - 1;
      } else gabs = rt;
      aReg[i] = *reinterpret_cast<const int4*>(A + (size_t)gabs * K + kb + a_k);
    }
  };
  auto writeA = [&](int buf) {
#pragma unroll
    for (int i = 0; i < 2; ++i)
      *reinterpret_cast<int4*>(&Ab[buf][a_r0 + i * 128][a_k]) = aReg[i];
  };
  auto loadB = [&](int kt) {
    const int kb = kt << 5;
#pragma unroll
    for (int kk = 0; kk < 2; ++kk)
      bReg[kk] = *reinterpret_cast<const float2*>(B + (size_t)(kb + b_k0 + kk) * N + ntile + b_n0);
  };
  auto writeB = [&](int buf) {
#pragma unroll
    for (int nn = 0; nn < 2; ++nn) {
      const int n = b_n0 + nn;
      const int kp = (b_k0 & 7) | ((((b_k0 >> 3) ^ n) & 3) << 3);
      short2v p;
      p[0] = f2bf(nn ? bReg[0].y : bReg[0].x);
      p[1] = f2bf(nn ? bReg[1].y : bReg[1].x);
      *reinterpret_cast<short2v*>(&Bb[buf][n][kp]) = p;
    }
  };

  const int lrow = lane & 15;
  const int lkg = lane >> 4;
  auto compute = [&](int buf) {
    bf16x8 af[4], bfv[2];
#pragma unroll
    for (int mf = 0; mf < 4; ++mf)
      af[mf] = *reinterpret_cast<const bf16x8*>(&Ab[buf][wm + mf * 16 + lrow][lkg << 3]);
#pragma unroll
    for (int nf = 0; nf < 2; ++nf) {
      const int n = wn + nf * 16 + lrow;
      const int kg = ((lkg ^ n) & 3) << 3;
      bfv[nf] = *reinterpret_cast<const bf16x8*>(&Bb[buf][n][kg]);
    }
#pragma unroll
    for (int mf = 0; mf < 4; ++mf)
#pragma unroll
      for (int nf = 0; nf < 2; ++nf)
        acc[mf][nf] = __builtin_amdgcn_mfma_f32_16x16x32_bf16(af[mf], bfv[nf], acc[mf][nf], 0, 0, 0);
  };

  loadA(0); loadB(0);
  writeA(0); writeB(0);
  __syncthreads();
  for (int kt = 0; kt < KT; ++kt) {
    const int buf = kt & 1;
    if (kt + 1 < KT) { loadA(kt + 1); loadB(kt + 1); }
    compute(buf);
    if (kt + 1 < KT) { writeA(buf ^ 1); writeB(buf ^ 1); }
    __syncthreads();
  }

#pragma unroll
  for (int mf = 0; mf < 4; ++mf) {
#pragma unroll
    for (int r = 0; r < 4; ++r) {
      const int rtile = wm + mf * 16 + ((lane >> 4) << 2) + r;
      const int col = ntile + wn + (lane & 15);
      if (MODE == 2) {
        if (mtile + rtile < cnt) {
          const int gr = rowbase + mtile + rtile;
          const int pid = rowmap[gr];
          const float wwv = wrow[gr];
          float* o = Out + (size_t)pid * N + col;
#pragma unroll
          for (int nf = 0; nf < 2; ++nf) o[nf * 16] = wwv * acc[mf][nf][r];
        }
      } else {
        const int t = mtile + rtile;
        const float* p0 = pairs + (size_t)(2 * t) * N + col;
        const float* p1 = p0 + N;
        float* o = Out + (size_t)t * N + col;
#pragma unroll
        for (int nf = 0; nf < 2; ++nf) o[nf * 16] = acc[mf][nf][r] + p0[nf * 16] + p1[nf * 16];
      }
    }
  }
}

extern "C" void kernel_launch(void* const* d_in, const int* in_sizes, int n_in,
                              void* d_out, int out_size, void* d_ws, size_t ws_size,
                              hipStream_t stream) {
  const float* x  = (const float*)d_in[0];
  const float* rw = (const float*)d_in[1];
  const float* w1 = (const float*)d_in[2];
  const float* w3 = (const float*)d_in[3];
  const float* w2 = (const float*)d_in[4];
  const float* sg = (const float*)d_in[5];
  const float* su = (const float*)d_in[6];
  const float* sd = (const float*)d_in[7];
  float* out = (float*)d_out;
  (void)in_sizes; (void)n_in; (void)out_size; (void)ws_size;

  char* ws = (char*)d_ws;
  size_t off = 0;
  auto alloc = [&](size_t bytes) -> void* {
    void* p = ws + off;
    off = (off + bytes + 255) & ~(size_t)255;
    return p;
  };
  int*   counts  = (int*)alloc(NEXP * 4);          // @0
  int*   slotc   = (int*)alloc(NEXP * 4);          // @256
  int*   offsets = (int*)alloc(NEXP * 4);
  int*   tidx    = (int*)alloc(NPAIR * 4);
  float* tw      = (float*)alloc(NPAIR * 4);
  int*   rowmap  = (int*)alloc(NPAIR * 4);
  float* wrowv   = (float*)alloc(NPAIR * 4);
  short* xb      = (short*)alloc((size_t)TOKENS * HDIM * 2);
  short* xg      = (short*)alloc((size_t)NPAIR * HDIM * 2);
  short* hbuf    = (short*)alloc((size_t)NPAIR * IDIM * 2);   // == TOKENS*ISDIM
  float* pairs   = (float*)alloc((size_t)NPAIR * HDIM * 4);

  hipMemsetAsync(d_ws, 0, 512, stream);  // zero counts + slotc

  router_kernel<<<dim3(TOKENS), dim3(64), 0, stream>>>(x, rw, counts, tidx, tw);
  scan_kernel<<<dim3(1), dim3(64), 0, stream>>>(counts, offsets);
  gather_kernel<<<dim3(TOKENS), dim3(256), 0, stream>>>(x, tidx, tw, offsets, slotc,
                                                        rowmap, wrowv, xb, xg);

  // sparse experts: fused w1/w3 + silu -> hbuf, then w2 down-proj -> pairs
  moe_up<true><<<dim3(IDIM / 64, 16, NEXP), dim3(512), 0, stream>>>(
      xg, w1, w3, hbuf, HDIM, IDIM, counts, offsets, NPAIR);
  moe_down<2><<<dim3(HDIM / 64, 16, NEXP), dim3(512), 0, stream>>>(
      hbuf, w2, pairs, IDIM, HDIM, counts, offsets, rowmap, wrowv, nullptr, NPAIR);

  // shared MLP: fused gate/up + silu -> hbuf, then down + pair-combine -> out
  moe_up<false><<<dim3(ISDIM / 64, TOKENS / 256, 1), dim3(512), 0, stream>>>(
      xb, sg, su, hbuf, HDIM, ISDIM, nullptr, nullptr, TOKENS);
  moe_down<3><<<dim3(HDIM / 64, TOKENS / 256, 1), dim3(512), 0, stream>>>(
      hbuf, sd, out, ISDIM, HDIM, nullptr, nullptr, nullptr, nullptr, pairs, TOKENS);
}

// Round 4
// 1069.433 us; speedup vs baseline: 1.3713x; 1.2206x over previous
//
#include <hip/hip_runtime.h>
#include <hip/hip_bf16.h>

#define TOKENS 2048
#define HDIM   2560
#define NEXP   16
#define IDIM   1664
#define ISDIM  3328
#define NPAIR  (TOKENS*2)

typedef float  f32x4   __attribute__((ext_vector_type(4)));
typedef __bf16 bf16x8  __attribute__((ext_vector_type(8)));
typedef short  short8v __attribute__((ext_vector_type(8)));

#define GLDS16(g, l) __builtin_amdgcn_global_load_lds( \
    (const __attribute__((address_space(1))) unsigned int*)(g), \
    (__attribute__((address_space(3))) unsigned int*)(l), 16, 0, 0)

__device__ __forceinline__ short f2bf(float f) {
  unsigned u = __builtin_bit_cast(unsigned, f);
  u += 0x7FFFu + ((u >> 16) & 1u);          // RNE to bf16
  return (short)(u >> 16);
}

// ---------------- router: fp32 logits, softmax-top2-renorm == sigmoid(l0-l1)
__global__ void router_kernel(const float* __restrict__ x, const float* __restrict__ rw,
                              int* __restrict__ counts, int* __restrict__ tidx,
                              float* __restrict__ tw) {
  const int t = blockIdx.x;
  const int lane = threadIdx.x;
  float acc[NEXP];
#pragma unroll
  for (int e = 0; e < NEXP; ++e) acc[e] = 0.f;
  const float* xr = x + (size_t)t * HDIM;
  for (int k = lane; k < HDIM; k += 64) {
    float xv = xr[k];
#pragma unroll
    for (int e = 0; e < NEXP; ++e) acc[e] += xv * rw[e * HDIM + k];
  }
#pragma unroll
  for (int e = 0; e < NEXP; ++e) {
#pragma unroll
    for (int o = 32; o > 0; o >>= 1) acc[e] += __shfl_down(acc[e], o);
  }
  if (lane == 0) {
    int i0 = 0; float v0 = acc[0];
#pragma unroll
    for (int e = 1; e < NEXP; ++e) if (acc[e] > v0) { v0 = acc[e]; i0 = e; }
    int i1 = -1; float v1 = -3.4e38f;
#pragma unroll
    for (int e = 0; e < NEXP; ++e) if (e != i0 && acc[e] > v1) { v1 = acc[e]; i1 = e; }
    float w0 = 1.f / (1.f + expf(v1 - v0));
    tidx[t * 2] = i0; tidx[t * 2 + 1] = i1;
    tw[t * 2] = w0;   tw[t * 2 + 1] = 1.f - w0;
    atomicAdd(&counts[i0], 1);
    atomicAdd(&counts[i1], 1);
  }
}

__global__ void scan_kernel(const int* __restrict__ counts, int* __restrict__ offsets) {
  if (threadIdx.x == 0) {
    int a = 0;
    for (int e = 0; e < NEXP; ++e) { offsets[e] = a; a += counts[e]; }
  }
}

// ---------------- bucket pairs + gather bf16 activations
__global__ void gather_kernel(const float* __restrict__ x, const int* __restrict__ tidx,
                              const float* __restrict__ tw, const int* __restrict__ offsets,
                              int* __restrict__ slotc, int* __restrict__ pairpos,
                              float* __restrict__ wrow, short* __restrict__ xb,
                              short* __restrict__ xg) {
  const int t = blockIdx.x, tid = threadIdx.x;
  __shared__ int grs[2];
  if (tid < 2) {
    int e = tidx[t * 2 + tid];
    int slot = atomicAdd(&slotc[e], 1);
    int g = offsets[e] + slot;
    grs[tid] = g;
    pairpos[t * 2 + tid] = g;
    wrow[g] = tw[t * 2 + tid];
  }
  __syncthreads();
  const int g0 = grs[0], g1 = grs[1];
  const float* xr = x + (size_t)t * HDIM;
#pragma unroll
  for (int i = 0; i < HDIM / 256; ++i) {
    int k = tid + i * 256;
    short v = f2bf(xr[k]);
    xb[(size_t)t * HDIM + k] = v;
    xg[(size_t)g0 * HDIM + k] = v;
    xg[(size_t)g1 * HDIM + k] = v;
  }
}

// ================= merged UP: H = bf16( silu(A*B1) * (A*B3) )
// A bf16 (M,K=2560) K-contig; B fp32 (K,N) N-contig.  BM=256, BN=128, BK=32.
// 1024 threads, 16 waves (8 M x 2 N), wave tile 32x64.
// LDS: A linear [256][32] (global_load_lds), B transposed [n][k] with
// kg' = kg ^ ((n>>1)&3) swizzle (conflict-free b128 write+read).
__launch_bounds__(1024, 4)
__global__ void moe_up_k(const short* __restrict__ xg, const short* __restrict__ xb,
                         const float* __restrict__ w1, const float* __restrict__ w3,
                         const float* __restrict__ sg, const float* __restrict__ su,
                         short* __restrict__ hbE, short* __restrict__ hbS,
                         const int* __restrict__ counts, const int* __restrict__ offsets) {
  const int tid = threadIdx.x;
  const int lin = blockIdx.x;
  const short* A; const float* B1; const float* B3; short* H;
  int N, mtile, ntile, rowbase = 0, cnt = 0x7fffffff;
  bool expert;
  if (lin < 13 * 16 * NEXP) {
    // XCD chunk (consecutive idx per XCD); m fastest so the ~2 live m-tiles
    // of an (e,n) are adjacent -> B panel L2 hit; A panels L2-resident per e.
    int idx = (lin & 7) * 416 + (lin >> 3);
    int m = idx & 15;
    int rest = idx >> 4;          // 0..207
    int n = rest % 13;
    int e = rest / 13;
    cnt = counts[e];
    mtile = m * 256;
    if (mtile >= cnt) return;
    rowbase = offsets[e];
    A = xg; B1 = w1 + (size_t)e * HDIM * IDIM; B3 = w3 + (size_t)e * HDIM * IDIM;
    H = hbE; N = IDIM; ntile = n * 128; expert = true;
  } else {
    int s = lin - 13 * 16 * NEXP;   // 0..255
    int n = s % 26;
    int m = s / 26;
    if (m >= 8) return;
    mtile = m * 256;
    A = xb; B1 = sg; B3 = su; H = hbS; N = ISDIM; ntile = n * 128; expert = false;
  }
  const int K = HDIM;
  const int KT = HDIM / 32;

  __shared__ short Ab[2][256][32];       // 16 KB x2, linear
  __shared__ short Bb[2][2][128][32];    // 16 KB x2 x2, swizzled [n][k]

  f32x4 accG[2][4], accU[2][4];
#pragma unroll
  for (int i = 0; i < 2; ++i)
#pragma unroll
    for (int j = 0; j < 4; ++j) { f32x4 z = {0.f,0.f,0.f,0.f}; accG[i][j] = z; accU[i][j] = z; }

  // A staging: row = tid>>2, k-oct = tid&3
  const int a_row = tid >> 2;
  int a_gr = expert ? (rowbase + mtile + a_row) : (mtile + a_row);
  if (a_gr > NPAIR - 1) a_gr = NPAIR - 1;
  const short* a_src_base = A + (size_t)a_gr * K + ((tid & 3) << 3);

  // B staging: matrix sm, col n, k-octet oct
  const int b_sm  = tid >> 9;
  const int b_n   = tid & 127;
  const int b_oct = (tid >> 7) & 3;
  const float* b_src_base = (b_sm ? B3 : B1) + (size_t)(b_oct * 8) * N + ntile + b_n;
  const int b_kg = (b_oct ^ ((b_n >> 1) & 3)) << 3;
  float bv[8];

  auto stageA = [&](int kt, int buf) {
    GLDS16(a_src_base + (kt << 5), (short*)Ab[buf] + tid * 8);
  };
  auto loadB = [&](int kt) {
    const float* p = b_src_base + (size_t)(kt << 5) * N;
#pragma unroll
    for (int j = 0; j < 8; ++j) bv[j] = p[(size_t)j * N];
  };
  auto writeB = [&](int buf) {
    short8v s;
#pragma unroll
    for (int j = 0; j < 8; ++j) s[j] = f2bf(bv[j]);
    *reinterpret_cast<short8v*>(&Bb[buf][b_sm][b_n][b_kg]) = s;
  };

  const int lane = tid & 63;
  const int w = tid >> 6;
  const int wm = (w >> 1) * 32;
  const int wn = (w & 1) * 64;
  const int lrow = lane & 15;
  const int lkg = lane >> 4;

  auto compute = [&](int buf) {
    bf16x8 af[2], bG[4], bU[4];
#pragma unroll
    for (int mf = 0; mf < 2; ++mf)
      af[mf] = *reinterpret_cast<const bf16x8*>(&Ab[buf][wm + mf * 16 + lrow][lkg << 3]);
#pragma unroll
    for (int nf = 0; nf < 4; ++nf) {
      const int n = wn + nf * 16 + lrow;
      const int kg = (lkg ^ ((n >> 1) & 3)) << 3;
      bG[nf] = *reinterpret_cast<const bf16x8*>(&Bb[buf][0][n][kg]);
      bU[nf] = *reinterpret_cast<const bf16x8*>(&Bb[buf][1][n][kg]);
    }
#pragma unroll
    for (int mf = 0; mf < 2; ++mf)
#pragma unroll
      for (int nf = 0; nf < 4; ++nf) {
        accG[mf][nf] = __builtin_amdgcn_mfma_f32_16x16x32_bf16(af[mf], bG[nf], accG[mf][nf], 0, 0, 0);
        accU[mf][nf] = __builtin_amdgcn_mfma_f32_16x16x32_bf16(af[mf], bU[nf], accU[mf][nf], 0, 0, 0);
      }
  };

  loadB(0); stageA(0, 0); writeB(0);
  __syncthreads();
  for (int kt = 0; kt < KT; ++kt) {
    const int buf = kt & 1;
    if (kt + 1 < KT) { stageA(kt + 1, buf ^ 1); loadB(kt + 1); }
    compute(buf);
    if (kt + 1 < KT) writeB(buf ^ 1);
    __syncthreads();
  }

  // epilogue: silu(g)*u -> bf16. C/D: col=lane&15, row=(lane>>4)*4+r
#pragma unroll
  for (int mf = 0; mf < 2; ++mf) {
#pragma unroll
    for (int r = 0; r < 4; ++r) {
      const int rt = wm + mf * 16 + ((lane >> 4) << 2) + r;
      if (expert && mtile + rt >= cnt) continue;
      const size_t grow = (size_t)((expert ? rowbase : 0) + mtile + rt);
      const int colb = ntile + wn + lrow;
#pragma unroll
      for (int nf = 0; nf < 4; ++nf) {
        float g = accG[mf][nf][r];
        float u = accU[mf][nf][r];
        H[grow * N + colb + nf * 16] = f2bf(g / (1.f + expf(-g)) * u);
      }
    }
  }
}

// ================= merged DOWN: Out = A*B.  BM=256, BN=128, BK=32, 512 thr,
// 8 waves (4M x 2N), wave tile 64x64.
// expert: A=hbE (K=1664), B=w2[e], out=pairs[gr] (dense, scaled by wrow).
// shared: A=hbS (K=3328), B=sd, out=plain (combine kernel adds pairs).
__launch_bounds__(512, 4)
__global__ void moe_dn_k(const short* __restrict__ hbE, const short* __restrict__ hbS,
                         const float* __restrict__ w2, const float* __restrict__ sd,
                         float* __restrict__ pairs, float* __restrict__ outb,
                         const int* __restrict__ counts, const int* __restrict__ offsets,
                         const float* __restrict__ wrow) {
  const int tid = threadIdx.x;
  const int lin = blockIdx.x;
  const short* A; const float* B; float* Out;
  int K, KT, mtile, ntile, rowbase = 0, cnt = 0x7fffffff;
  bool expert;
  if (lin < 20 * 16 * NEXP) {
    int idx = (lin & 7) * 640 + (lin >> 3);
    int m = idx & 15;
    int rest = idx >> 4;          // 0..319
    int n = rest % 20;
    int e = rest / 20;
    cnt = counts[e];
    mtile = m * 256;
    if (mtile >= cnt) return;
    rowbase = offsets[e];
    A = hbE; B = w2 + (size_t)e * IDIM * HDIM;
    Out = pairs; K = IDIM; KT = IDIM / 32; ntile = n * 128; expert = true;
  } else {
    int s = lin - 20 * 16 * NEXP;   // 0..191
    int n = s % 20;
    int m = s / 20;
    if (m >= 8) return;
    mtile = m * 256;
    A = hbS; B = sd; Out = outb; K = ISDIM; KT = ISDIM / 32; ntile = n * 128;
    expert = false;
  }

  __shared__ short Ab[2][256][32];
  __shared__ short Bb[2][128][32];

  f32x4 acc[4][4];
#pragma unroll
  for (int i = 0; i < 4; ++i)
#pragma unroll
    for (int j = 0; j < 4; ++j) { f32x4 z = {0.f,0.f,0.f,0.f}; acc[i][j] = z; }

  // A: 2 passes of 512 units
  int a_gr[2];
#pragma unroll
  for (int p = 0; p < 2; ++p) {
    int row = (tid + (p << 9)) >> 2;
    int gr = expert ? (rowbase + mtile + row) : (mtile + row);
    if (gr > NPAIR - 1) gr = NPAIR - 1;
    a_gr[p] = gr;
  }
  const int a_ko = (tid & 3) << 3;

  const int b_n   = tid & 127;
  const int b_oct = tid >> 7;
  const float* b_src_base = B + (size_t)(b_oct * 8) * HDIM + ntile + b_n;
  const int b_kg = (b_oct ^ ((b_n >> 1) & 3)) << 3;
  float bv[8];

  auto stageA = [&](int kt, int buf) {
#pragma unroll
    for (int p = 0; p < 2; ++p) {
      const short* src = A + (size_t)a_gr[p] * K + (kt << 5) + a_ko;
      GLDS16(src, (short*)Ab[buf] + (tid + (p << 9)) * 8);
    }
  };
  auto loadB = [&](int kt) {
    const float* p = b_src_base + (size_t)(kt << 5) * HDIM;
#pragma unroll
    for (int j = 0; j < 8; ++j) bv[j] = p[(size_t)j * HDIM];
  };
  auto writeB = [&](int buf) {
    short8v s;
#pragma unroll
    for (int j = 0; j < 8; ++j) s[j] = f2bf(bv[j]);
    *reinterpret_cast<short8v*>(&Bb[buf][b_n][b_kg]) = s;
  };

  const int lane = tid & 63;
  const int w = tid >> 6;
  const int wm = (w >> 1) * 64;
  const int wn = (w & 1) * 64;
  const int lrow = lane & 15;
  const int lkg = lane >> 4;

  auto compute = [&](int buf) {
    bf16x8 af[4], bfv[4];
#pragma unroll
    for (int mf = 0; mf < 4; ++mf)
      af[mf] = *reinterpret_cast<const bf16x8*>(&Ab[buf][wm + mf * 16 + lrow][lkg << 3]);
#pragma unroll
    for (int nf = 0; nf < 4; ++nf) {
      const int n = wn + nf * 16 + lrow;
      const int kg = (lkg ^ ((n >> 1) & 3)) << 3;
      bfv[nf] = *reinterpret_cast<const bf16x8*>(&Bb[buf][n][kg]);
    }
#pragma unroll
    for (int mf = 0; mf < 4; ++mf)
#pragma unroll
      for (int nf = 0; nf < 4; ++nf)
        acc[mf][nf] = __builtin_amdgcn_mfma_f32_16x16x32_bf16(af[mf], bfv[nf], acc[mf][nf], 0, 0, 0);
  };

  loadB(0); stageA(0, 0); writeB(0);
  __syncthreads();
  for (int kt = 0; kt < KT; ++kt) {
    const int buf = kt & 1;
    if (kt + 1 < KT) { stageA(kt + 1, buf ^ 1); loadB(kt + 1); }
    compute(buf);
    if (kt + 1 < KT) writeB(buf ^ 1);
    __syncthreads();
  }

#pragma unroll
  for (int mf = 0; mf < 4; ++mf) {
#pragma unroll
    for (int r = 0; r < 4; ++r) {
      const int rt = wm + mf * 16 + ((lane >> 4) << 2) + r;
      const int colb = ntile + wn + lrow;
      if (expert) {
        if (mtile + rt < cnt) {
          const int gr = rowbase + mtile + rt;
          const float sc = wrow[gr];
          float* o = Out + (size_t)gr * HDIM + colb;
#pragma unroll
          for (int nf = 0; nf < 4; ++nf) o[nf * 16] = sc * acc[mf][nf][r];
        }
      } else {
        float* o = Out + (size_t)(mtile + rt) * HDIM + colb;
#pragma unroll
        for (int nf = 0; nf < 4; ++nf) o[nf * 16] = acc[mf][nf][r];
      }
    }
  }
}

// ---------------- final combine: out[t] += pairs[g0] + pairs[g1]
// (grid-stride over the full 640 f32x4 per row — R3 bug was truncated 2.5->2)
__global__ void combine_kernel(float* __restrict__ out, const float* __restrict__ pairs,
                               const int* __restrict__ pairpos) {
  const int t = blockIdx.x;
  const int g0 = pairpos[t * 2], g1 = pairpos[t * 2 + 1];
  const f32x4* p0 = (const f32x4*)(pairs + (size_t)g0 * HDIM);
  const f32x4* p1 = (const f32x4*)(pairs + (size_t)g1 * HDIM);
  f32x4* o = (f32x4*)(out + (size_t)t * HDIM);
  for (int c = threadIdx.x; c < HDIM / 4; c += 256)
    o[c] = o[c] + p0[c] + p1[c];
}

extern "C" void kernel_launch(void* const* d_in, const int* in_sizes, int n_in,
                              void* d_out, int out_size, void* d_ws, size_t ws_size,
                              hipStream_t stream) {
  const float* x  = (const float*)d_in[0];
  const float* rw = (const float*)d_in[1];
  const float* w1 = (const float*)d_in[2];
  const float* w3 = (const float*)d_in[3];
  const float* w2 = (const float*)d_in[4];
  const float* sg = (const float*)d_in[5];
  const float* su = (const float*)d_in[6];
  const float* sd = (const float*)d_in[7];
  float* out = (float*)d_out;
  (void)in_sizes; (void)n_in; (void)out_size; (void)ws_size;

  char* ws = (char*)d_ws;
  size_t off = 0;
  auto alloc = [&](size_t bytes) -> void* {
    void* p = ws + off;
    off = (off + bytes + 255) & ~(size_t)255;
    return p;
  };
  int*   counts  = (int*)alloc(NEXP * 4);          // @0
  int*   slotc   = (int*)alloc(NEXP * 4);          // @256
  int*   offsets = (int*)alloc(NEXP * 4);
  int*   tidx    = (int*)alloc(NPAIR * 4);
  float* tw      = (float*)alloc(NPAIR * 4);
  float* wrowv   = (float*)alloc(NPAIR * 4);
  int*   pairpos = (int*)alloc(NPAIR * 4);
  short* xb      = (short*)alloc((size_t)TOKENS * HDIM * 2);
  short* xg      = (short*)alloc((size_t)NPAIR * HDIM * 2);
  short* hbE     = (short*)alloc((size_t)NPAIR * IDIM * 2);
  short* hbS     = (short*)alloc((size_t)TOKENS * ISDIM * 2);
  float* pairs   = (float*)alloc((size_t)NPAIR * HDIM * 4);

  hipMemsetAsync(d_ws, 0, 512, stream);  // zero counts + slotc

  router_kernel<<<dim3(TOKENS), dim3(64), 0, stream>>>(x, rw, counts, tidx, tw);
  scan_kernel<<<dim3(1), dim3(64), 0, stream>>>(counts, offsets);
  gather_kernel<<<dim3(TOKENS), dim3(256), 0, stream>>>(x, tidx, tw, offsets, slotc,
                                                        pairpos, wrowv, xb, xg);

  // merged up: experts (16m x 13n x 16e = 3328) + shared (256-slot region)
  moe_up_k<<<dim3(13 * 16 * NEXP + 256), dim3(1024), 0, stream>>>(
      xg, xb, w1, w3, sg, su, hbE, hbS, counts, offsets);

  // merged down: experts (16m x 20n x 16e = 5120) + shared (192-slot region)
  moe_dn_k<<<dim3(20 * 16 * NEXP + 192), dim3(512), 0, stream>>>(
      hbE, hbS, w2, sd, pairs, out, counts, offsets, wrowv);

  combine_kernel<<<dim3(TOKENS), dim3(256), 0, stream>>>(out, pairs, pairpos);
}